// Round 7
// baseline (164.833 us; speedup 1.0000x reference)
//
#include <hip/hip_runtime.h>

#define C_SEG 4096
#define E_CH 16
#define NE_EDGES 16384
#define P_PIX (1024 * 1024)
#define NCHUNK 32
#define CHUNK_PIX (P_PIX / NCHUNK)   // 32768
#define SCALE 262144.0f              // 2^18 fixed point
#define INV_SCALE (1.0f / 262144.0f)

// ws layout (byte offsets):
//   0x000000  sums_part[16][32][4096] f32    8 MB
//   0x800000  cnt_part[32][4096]      f32  512 KB
//   0x880000  msum[4096][16]          f32  256 KB   (UNnormalized sums)
//   0x8C0000  inv_n[4096]             f32   16 KB
//   0x8C4000  part[1024]              f32    4 KB
//   0x8C5000  counter                 int     4 B   (zeroed by kB)

// ---------------------------------------------------------------------------
// kA: R3's measured-best segsum config, verbatim. grid (32 chunks, 17 groups)
// x 512 thr, 16 KB int bins, NO min-wave cap (R6's (512,8)=64-VGPR cap
// regressed), no software prefetch. g==16 does counts. Fire-and-forget
// native ds_add_u32; deterministic fixed-point partials.
// ---------------------------------------------------------------------------
__global__ __launch_bounds__(512) void kA(const float* __restrict__ emb,
                                          const int* __restrict__ seg,
                                          float* __restrict__ sums_part,
                                          float* __restrict__ cnt_part) {
    __shared__ int bins[C_SEG];  // 16 KB
    const int chunk = blockIdx.x;
    const int g = blockIdx.y;
    const int t = threadIdx.x;
    const int base = chunk * CHUNK_PIX;

    for (int i = t; i < C_SEG; i += 512) bins[i] = 0;
    __syncthreads();

    if (g == 16) {
        for (int it = 0; it < 16; ++it) {
            const int idx = base + (it * 512 + t) * 4;
            const int4 s4 = *(const int4*)(seg + idx);
            atomicAdd(&bins[s4.x], 1);
            atomicAdd(&bins[s4.y], 1);
            atomicAdd(&bins[s4.z], 1);
            atomicAdd(&bins[s4.w], 1);
        }
        __syncthreads();
        float* cd = cnt_part + (size_t)chunk * C_SEG;
        for (int i = t; i < C_SEG; i += 512) cd[i] = (float)bins[i];
    } else {
        const float* ec = emb + (size_t)g * P_PIX;
        for (int it = 0; it < 16; ++it) {
            const int idx = base + (it * 512 + t) * 4;
            const int4 s4 = *(const int4*)(seg + idx);
            const float4 v = *(const float4*)(ec + idx);
            atomicAdd(&bins[s4.x], __float2int_rn(v.x * SCALE));
            atomicAdd(&bins[s4.y], __float2int_rn(v.y * SCALE));
            atomicAdd(&bins[s4.z], __float2int_rn(v.z * SCALE));
            atomicAdd(&bins[s4.w], __float2int_rn(v.w * SCALE));
        }
        __syncthreads();
        float* dst = sums_part + ((size_t)g * NCHUNK + chunk) * C_SEG;
        for (int i = t; i < C_SEG; i += 512)
            dst[i] = (float)bins[i] * INV_SCALE;
    }
}

// ---------------------------------------------------------------------------
// kB: merge chunk partials. 272 blocks x 256. vb<256: sums (coalesced over
// segs); vb in [256,272): counts -> inv_n. Block 0 also zeroes the kC
// completion counter (kernel-boundary ordering guarantees visibility).
// ---------------------------------------------------------------------------
__global__ __launch_bounds__(256) void kB(const float* __restrict__ sums_part,
                                          const float* __restrict__ cnt_part,
                                          float* __restrict__ msum,
                                          float* __restrict__ inv_n,
                                          int* __restrict__ counter) {
    const int vb = blockIdx.x, t = threadIdx.x;
    if (vb == 0 && t == 0) *counter = 0;
    if (vb < 256) {
        const int c = vb >> 4;
        const int s = (vb & 15) * 256 + t;
        const float* src = sums_part + (size_t)c * NCHUNK * C_SEG + s;
        float acc = 0.0f;
#pragma unroll
        for (int k = 0; k < NCHUNK; ++k) acc += src[(size_t)k * C_SEG];
        msum[s * E_CH + c] = acc;  // UNnormalized
    } else {
        const int s = (vb - 256) * 256 + t;
        float acc = 0.0f;
#pragma unroll
        for (int k = 0; k < NCHUNK; ++k) acc += cnt_part[(size_t)k * C_SEG + s];
        inv_n[s] = 1.0f / fmaxf(acc, 1.0f);
    }
}

// ---------------------------------------------------------------------------
// kC: intra (4 px/thread, float4) + 16 edges/block, 1024 blocks x 256.
// Final reduction folded in via last-block-done counter (saves kF launch).
// ---------------------------------------------------------------------------
__global__ __launch_bounds__(256, 4) void kC(const float* __restrict__ emb,
                                             const int* __restrict__ seg,
                                             const int* __restrict__ edges,
                                             const float* __restrict__ w,
                                             const float* __restrict__ msum,
                                             const float* __restrict__ inv_n,
                                             float* __restrict__ part,
                                             int* __restrict__ counter,
                                             float* __restrict__ out) {
    const int b = blockIdx.x, t = threadIdx.x;
    const int q = b * 256 + t;  // quad index, 262144 total
    const int4 s4 = *(const int4*)(seg + q * 4);
    const float inx = inv_n[s4.x], iny = inv_n[s4.y];
    const float inz = inv_n[s4.z], inw = inv_n[s4.w];
    const float4* emb4 = (const float4*)emb;
    const float4* rA = (const float4*)(msum + s4.x * E_CH);
    const float4* rB = (const float4*)(msum + s4.y * E_CH);
    const float4* rC = (const float4*)(msum + s4.z * E_CH);
    const float4* rD = (const float4*)(msum + s4.w * E_CH);

    float dx = 0.f, dy = 0.f, dz = 0.f, dw = 0.f;
#pragma unroll
    for (int j = 0; j < 4; ++j) {
        const float4 a = rA[j], b4 = rB[j], c4 = rC[j], d4 = rD[j];
        const float* aF = (const float*)&a;
        const float* bF = (const float*)&b4;
        const float* cF = (const float*)&c4;
        const float* dF = (const float*)&d4;
#pragma unroll
        for (int cc = 0; cc < 4; ++cc) {
            const float4 e = emb4[(size_t)(j * 4 + cc) * (P_PIX / 4) + q];
            dx = fmaf(e.x, aF[cc], dx);
            dy = fmaf(e.y, bF[cc], dy);
            dz = fmaf(e.z, cF[cc], dz);
            dw = fmaf(e.w, dF[cc], dw);
        }
    }
    // dot_p = inv_n * sdot; term = max(0.5 - dot_p, 0) * inv_n
    float v = (fmaxf(0.5f - inx * dx, 0.0f) * inx +
               fmaxf(0.5f - iny * dy, 0.0f) * iny +
               fmaxf(0.5f - inz * dz, 0.0f) * inz +
               fmaxf(0.5f - inw * dw, 0.0f) * inw) *
              (1.0f / (float)C_SEG);

    if (t < 16) {  // 16 edges per block
        const int e = b * 16 + t;
        const int u = edges[e];
        const int vv = edges[NE_EDGES + e];
        const float4* mu = (const float4*)(msum + u * E_CH);
        const float4* mv = (const float4*)(msum + vv * E_CH);
        float dot = 0.0f;
#pragma unroll
        for (int j = 0; j < 4; ++j) {
            const float4 a = mu[j];
            const float4 bb = mv[j];
            dot = fmaf(a.x, bb.x, dot);
            dot = fmaf(a.y, bb.y, dot);
            dot = fmaf(a.z, bb.z, dot);
            dot = fmaf(a.w, bb.w, dot);
        }
        const float d = 1.0f - inv_n[u] * inv_n[vv] * dot;
        v += fmaxf(1.5f - d * w[e], 0.0f) * (1.0f / (float)NE_EDGES);
    }

    for (int o = 32; o > 0; o >>= 1) v += __shfl_down(v, o, 64);
    __shared__ float red[4];
    __shared__ int lastflag;
    if ((t & 63) == 0) red[t >> 6] = v;
    __syncthreads();
    if (t == 0) {
        part[b] = red[0] + red[1] + red[2] + red[3];
        __threadfence();  // publish part[b] before counter bump
        lastflag = (atomicAdd(counter, 1) == 1023);
    }
    __syncthreads();
    if (lastflag) {
        __threadfence();  // acquire: see all other blocks' part[] writes
        const volatile float* pv = part;
        float f = 0.0f;
        for (int i = t; i < 1024; i += 256) f += pv[i];
        for (int o = 32; o > 0; o >>= 1) f += __shfl_down(f, o, 64);
        __syncthreads();  // red[] reuse guard
        if ((t & 63) == 0) red[t >> 6] = f;
        __syncthreads();
        if (t == 0) out[0] = red[0] + red[1] + red[2] + red[3];
    }
}

extern "C" void kernel_launch(void* const* d_in, const int* in_sizes, int n_in,
                              void* d_out, int out_size, void* d_ws,
                              size_t ws_size, hipStream_t stream) {
    const float* emb = (const float*)d_in[0];      // (1,16,1024,1024) fp32
    const float* weights = (const float*)d_in[1];  // (16384,) fp32
    const int* seg = (const int*)d_in[2];          // (1,1,1024,1024) int32
    const int* edges = (const int*)d_in[3];        // (2,16384) int32
    float* out = (float*)d_out;

    char* ws = (char*)d_ws;
    float* sums_part = (float*)(ws);
    float* cnt_part = (float*)(ws + 0x800000);
    float* msum = (float*)(ws + 0x880000);
    float* invn = (float*)(ws + 0x8C0000);
    float* part = (float*)(ws + 0x8C4000);
    int* counter = (int*)(ws + 0x8C5000);

    dim3 gA(NCHUNK, 17);
    kA<<<gA, 512, 0, stream>>>(emb, seg, sums_part, cnt_part);
    kB<<<272, 256, 0, stream>>>(sums_part, cnt_part, msum, invn, counter);
    kC<<<1024, 256, 0, stream>>>(emb, seg, edges, weights, msum, invn, part,
                                 counter, out);
}

// Round 8
// 133.849 us; speedup vs baseline: 1.2315x; 1.2315x over previous
//
#include <hip/hip_runtime.h>

#define C_SEG 4096
#define E_CH 16
#define NE_EDGES 16384
#define P_PIX (1024 * 1024)
#define NCHUNK 32
#define CHUNK_PIX (P_PIX / NCHUNK)   // 32768
#define SCALE 262144.0f              // 2^18 fixed point
#define INV_SCALE (1.0f / 262144.0f)

// ws layout (byte offsets):
//   0x000000  sums_part[16][32][4096] f32    8 MB
//   0x800000  cnt_part[32][4096]      f32  512 KB
//   0x880000  msum[4096][16]          f32  256 KB   (UNnormalized sums)
//   0x8C0000  inv_n[4096]             f32   16 KB
//   0x8C4000  part[1024]              f32    4 KB

// ---------------------------------------------------------------------------
// kA: R3's measured-best segsum config. grid (32 chunks, 17 groups) x 512,
// 16 KB int bins, no min-wave cap, no software prefetch. g==16 does counts.
// ---------------------------------------------------------------------------
__global__ __launch_bounds__(512) void kA(const float* __restrict__ emb,
                                          const int* __restrict__ seg,
                                          float* __restrict__ sums_part,
                                          float* __restrict__ cnt_part) {
    __shared__ int bins[C_SEG];  // 16 KB
    const int chunk = blockIdx.x;
    const int g = blockIdx.y;
    const int t = threadIdx.x;
    const int base = chunk * CHUNK_PIX;

    for (int i = t; i < C_SEG; i += 512) bins[i] = 0;
    __syncthreads();

    if (g == 16) {
        for (int it = 0; it < 16; ++it) {
            const int idx = base + (it * 512 + t) * 4;
            const int4 s4 = *(const int4*)(seg + idx);
            atomicAdd(&bins[s4.x], 1);
            atomicAdd(&bins[s4.y], 1);
            atomicAdd(&bins[s4.z], 1);
            atomicAdd(&bins[s4.w], 1);
        }
        __syncthreads();
        float* cd = cnt_part + (size_t)chunk * C_SEG;
        for (int i = t; i < C_SEG; i += 512) cd[i] = (float)bins[i];
    } else {
        const float* ec = emb + (size_t)g * P_PIX;
        for (int it = 0; it < 16; ++it) {
            const int idx = base + (it * 512 + t) * 4;
            const int4 s4 = *(const int4*)(seg + idx);
            const float4 v = *(const float4*)(ec + idx);
            atomicAdd(&bins[s4.x], __float2int_rn(v.x * SCALE));
            atomicAdd(&bins[s4.y], __float2int_rn(v.y * SCALE));
            atomicAdd(&bins[s4.z], __float2int_rn(v.z * SCALE));
            atomicAdd(&bins[s4.w], __float2int_rn(v.w * SCALE));
        }
        __syncthreads();
        float* dst = sums_part + ((size_t)g * NCHUNK + chunk) * C_SEG;
        for (int i = t; i < C_SEG; i += 512)
            dst[i] = (float)bins[i] * INV_SCALE;
    }
}

// ---------------------------------------------------------------------------
// kB: merge chunk partials. 272 blocks x 256. vb<256: sums (coalesced over
// segs); vb in [256,272): counts -> inv_n.
// ---------------------------------------------------------------------------
__global__ __launch_bounds__(256) void kB(const float* __restrict__ sums_part,
                                          const float* __restrict__ cnt_part,
                                          float* __restrict__ msum,
                                          float* __restrict__ inv_n) {
    const int vb = blockIdx.x, t = threadIdx.x;
    if (vb < 256) {
        const int c = vb >> 4;
        const int s = (vb & 15) * 256 + t;
        const float* src = sums_part + (size_t)c * NCHUNK * C_SEG + s;
        float acc = 0.0f;
#pragma unroll
        for (int k = 0; k < NCHUNK; ++k) acc += src[(size_t)k * C_SEG];
        msum[s * E_CH + c] = acc;  // UNnormalized
    } else {
        const int s = (vb - 256) * 256 + t;
        float acc = 0.0f;
#pragma unroll
        for (int k = 0; k < NCHUNK; ++k) acc += cnt_part[(size_t)k * C_SEG + s];
        inv_n[s] = 1.0f / fmaxf(acc, 1.0f);
    }
}

// ---------------------------------------------------------------------------
// kC: intra (4 px/thread) + 16 edges/block, 1024 blocks x 256.
// MLP-burst structure: issue ALL loads (4x4 mean-row gathers + 16 emb
// float4 streams) into register arrays before the FMA chain -> ~32
// outstanding loads/wave instead of R7's ~2 (VGPR_Count was 36 -> 61.5 us
// latency-bound at 603 GB/s; floor is ~6 us). No min-wave cap: let the
// allocator take ~150 VGPRs (2-3 blocks/CU is plenty at this MLP).
// ---------------------------------------------------------------------------
__global__ __launch_bounds__(256) void kC(const float* __restrict__ emb,
                                          const int* __restrict__ seg,
                                          const int* __restrict__ edges,
                                          const float* __restrict__ w,
                                          const float* __restrict__ msum,
                                          const float* __restrict__ inv_n,
                                          float* __restrict__ part) {
    const int b = blockIdx.x, t = threadIdx.x;
    const int q = b * 256 + t;  // quad index, 262144 total
    const int4 s4 = *(const int4*)(seg + q * 4);

    // issue gathers (dependent only on s4)
    float mA[16], mB[16], mC[16], mD[16];
#pragma unroll
    for (int j = 0; j < 4; ++j) {
        ((float4*)mA)[j] = ((const float4*)(msum + s4.x * E_CH))[j];
        ((float4*)mB)[j] = ((const float4*)(msum + s4.y * E_CH))[j];
        ((float4*)mC)[j] = ((const float4*)(msum + s4.z * E_CH))[j];
        ((float4*)mD)[j] = ((const float4*)(msum + s4.w * E_CH))[j];
    }
    const float inx = inv_n[s4.x], iny = inv_n[s4.y];
    const float inz = inv_n[s4.z], inw = inv_n[s4.w];

    // burst-load all 16 emb quads (64 VGPRs of results in flight)
    const float4* emb4 = (const float4*)emb;
    float4 e[16];
#pragma unroll
    for (int c = 0; c < 16; ++c) e[c] = emb4[(size_t)c * (P_PIX / 4) + q];

    float dx = 0.f, dy = 0.f, dz = 0.f, dw = 0.f;
#pragma unroll
    for (int c = 0; c < 16; ++c) {
        dx = fmaf(e[c].x, mA[c], dx);
        dy = fmaf(e[c].y, mB[c], dy);
        dz = fmaf(e[c].z, mC[c], dz);
        dw = fmaf(e[c].w, mD[c], dw);
    }

    float v = (fmaxf(0.5f - inx * dx, 0.0f) * inx +
               fmaxf(0.5f - iny * dy, 0.0f) * iny +
               fmaxf(0.5f - inz * dz, 0.0f) * inz +
               fmaxf(0.5f - inw * dw, 0.0f) * inw) *
              (1.0f / (float)C_SEG);

    if (t < 16) {  // 16 edges per block
        const int e2 = b * 16 + t;
        const int u = edges[e2];
        const int vv = edges[NE_EDGES + e2];
        const float4* mu = (const float4*)(msum + u * E_CH);
        const float4* mv = (const float4*)(msum + vv * E_CH);
        float dot = 0.0f;
#pragma unroll
        for (int j = 0; j < 4; ++j) {
            const float4 a = mu[j];
            const float4 bb = mv[j];
            dot = fmaf(a.x, bb.x, dot);
            dot = fmaf(a.y, bb.y, dot);
            dot = fmaf(a.z, bb.z, dot);
            dot = fmaf(a.w, bb.w, dot);
        }
        const float d = 1.0f - inv_n[u] * inv_n[vv] * dot;
        v += fmaxf(1.5f - d * w[e2], 0.0f) * (1.0f / (float)NE_EDGES);
    }

    for (int o = 32; o > 0; o >>= 1) v += __shfl_down(v, o, 64);
    __shared__ float red[4];
    if ((t & 63) == 0) red[t >> 6] = v;
    __syncthreads();
    if (t == 0) part[b] = red[0] + red[1] + red[2] + red[3];
}

// ---------------------------------------------------------------------------
// kF: sum 1024 partials -> scalar.
// ---------------------------------------------------------------------------
__global__ __launch_bounds__(256) void kF(const float* __restrict__ part,
                                          float* __restrict__ out) {
    float v = 0.0f;
    for (int i = threadIdx.x; i < 1024; i += 256) v += part[i];
    for (int o = 32; o > 0; o >>= 1) v += __shfl_down(v, o, 64);
    __shared__ float red[4];
    const int t = threadIdx.x;
    if ((t & 63) == 0) red[t >> 6] = v;
    __syncthreads();
    if (t == 0) out[0] = red[0] + red[1] + red[2] + red[3];
}

extern "C" void kernel_launch(void* const* d_in, const int* in_sizes, int n_in,
                              void* d_out, int out_size, void* d_ws,
                              size_t ws_size, hipStream_t stream) {
    const float* emb = (const float*)d_in[0];      // (1,16,1024,1024) fp32
    const float* weights = (const float*)d_in[1];  // (16384,) fp32
    const int* seg = (const int*)d_in[2];          // (1,1,1024,1024) int32
    const int* edges = (const int*)d_in[3];        // (2,16384) int32
    float* out = (float*)d_out;

    char* ws = (char*)d_ws;
    float* sums_part = (float*)(ws);
    float* cnt_part = (float*)(ws + 0x800000);
    float* msum = (float*)(ws + 0x880000);
    float* invn = (float*)(ws + 0x8C0000);
    float* part = (float*)(ws + 0x8C4000);

    dim3 gA(NCHUNK, 17);
    kA<<<gA, 512, 0, stream>>>(emb, seg, sums_part, cnt_part);
    kB<<<272, 256, 0, stream>>>(sums_part, cnt_part, msum, invn);
    kC<<<1024, 256, 0, stream>>>(emb, seg, edges, weights, msum, invn, part);
    kF<<<1, 256, 0, stream>>>(part, out);
}